// Round 1
// baseline (332.850 us; speedup 1.0000x reference)
//
#include <hip/hip_runtime.h>

constexpr int B = 2;
constexpr int N = 50000;
constexpr int D = 64;
constexpr int E = 800000;
constexpr int CAP = 96;        // Poisson(32) max degree over 50k nodes ~58; 96 = margin
constexpr int XG = 8;          // XCD groups
constexpr int NPG = N / XG;    // 6250 nodes per group
constexpr int ECHUNKS = E / 256;          // 3125 build chunks (x8 replicas = 25000 blocks)
constexpr int PBLOCKS = (B * N) / 4;      // 25000 pgemm blocks

typedef int v2i __attribute__((ext_vector_type(2)));

// ---- bf16 helpers (manual RTN) --------------------------------------------
__device__ __forceinline__ unsigned f2bf(float f) {
    unsigned u = __float_as_uint(f);
    return (u + 0x7FFFu + ((u >> 16) & 1u)) >> 16;
}
__device__ __forceinline__ float bfhi2f(unsigned bits) {
    return __uint_as_float(bits & 0xFFFF0000u);
}
__device__ __forceinline__ float bflo2f(unsigned bits) {
    return __uint_as_float(bits << 16);
}

// ===========================================================================
// 1) FUSED build + pgemm, one dispatch, 50000 blocks in groups of 8.
// L2-isolation version: every single-use stream (edges, status, prev, P32)
// is non-temporal so each XCD's L2 stays dedicated to its 2.4 MB slot
// region + counts (the only build data with write reuse). Previously the
// streams thrashed the dirty slot lines -> 81 MB writes / 63 MB fetches of
// 64B-line RMW traffic, which set the 113 us pace.
// ===========================================================================
__global__ __launch_bounds__(256) void build_pgemm_fused(
    const int2* __restrict__ edges, const float* __restrict__ status,
    int* __restrict__ counts, unsigned* __restrict__ slots,
    const float* __restrict__ prev, const float* __restrict__ W,
    unsigned* __restrict__ P32)
{
    __shared__ float Wl[D][D + 1];   // lane i reads Wl[i][d]: 2-way alias, free
    __shared__ float prow[4][D];     // per-wave prev row stage (broadcast reads)

    int grp = blockIdx.x >> 3;
    int sub8 = blockIdx.x & 7;
    int t = threadIdx.x;

    if ((grp & 1) == 0) {
        // ---- build replica: chunk = grp/2 in [0,3125), replica g = sub8 ----
        int e = (grp >> 1) * 256 + t;             // < E always (3125*256 == E)
        v2i uv = __builtin_nontemporal_load((const v2i*)edges + e);
        int u = uv.x, v = uv.y;
        unsigned gb = f2bf(__builtin_nontemporal_load(status + e)) << 16;

        bool du = (u / NPG == sub8);
        bool dv = (v / NPG == sub8);
        // issue both atomics before consuming either result: avoids
        // serializing atomic#2 behind atomic#1's round trip via the
        // divergent (p < CAP) branch.
        int pu = CAP, pv = CAP;
        if (du) pu = atomicAdd(&counts[u], 1);
        if (dv) pv = atomicAdd(&counts[v], 1);
        if (du && pu < CAP) slots[(size_t)u * CAP + pu] = gb | (unsigned)v;
        if (dv && pv < CAP) slots[(size_t)v * CAP + pv] = gb | (unsigned)u;
    } else {
        // ---- pgemm: block pb in [0,25000), 4 rows, wave = row --------------
        int pb = (grp >> 1) * 8 + sub8;
        for (int i = t; i < D * D; i += 256) Wl[i >> 6][i & 63] = W[i];
        __syncthreads();

        int wave = t >> 6, lane = t & 63;
        int row = __builtin_amdgcn_readfirstlane(pb * 4 + wave);
        // per-lane nt load of the prev row, staged via LDS (keeps the 25.6 MB
        // prev stream out of L2; old s_load path streamed through L2 too).
        float pvl = __builtin_nontemporal_load(prev + (size_t)row * D + lane);
        prow[wave][lane] = pvl;

        float acc = 0.f;
#pragma unroll
        for (int d = 0; d < D; ++d) acc += prow[wave][d] * Wl[lane][d];

        float partner = __shfl_xor(acc, 1, 64);     // feature lane^1
        if ((lane & 1) == 0) {
            unsigned packed = f2bf(acc) | (f2bf(partner) << 16);
            __builtin_nontemporal_store(packed, P32 + (size_t)row * 32 + (lane >> 1));
        }
    }
}

// ===========================================================================
// 2) Single-pass gather of P rows -> final output (round-7 structure).
// Wave = node (both batches). 8 subs x 8 lanes; per entry 2 x uint4 loads
// (128 B/batch). shfl-reduce across subs; LDS bounce for coalesced epilogue.
// nt on all single-use streams (slots, counts, node, edgef, out) so L2 is
// reserved for P rows (the only reused data: ~32 reads/row, random).
// ===========================================================================
__global__ __launch_bounds__(256) void gather_final(
    const uint4* __restrict__ P4,     // (B*N, 8) uint4 rows
    const int* __restrict__ counts,
    const unsigned* __restrict__ slots,
    const float* __restrict__ node,
    const float* __restrict__ edgef,
    float* __restrict__ out)
{
    __shared__ float xs[4][2][D];

    int t = threadIdx.x;
    int wave = t >> 6, lane = t & 63;
    int n = blockIdx.x * 4 + wave;    // grid = N/4 = 12500 exact
    int j = lane & 7;                 // uint4 chunk within row
    int sub = lane >> 3;              // 8-wide entry parallelism

    int cnt = min(__builtin_nontemporal_load(counts + n), CAP);
    size_t sbase = (size_t)n * CAP;

    float a0[8], a1[8];
#pragma unroll
    for (int i = 0; i < 8; ++i) { a0[i] = 0.f; a1[i] = 0.f; }

    for (int k = sub; k < cnt; k += 8) {
        unsigned ent = __builtin_nontemporal_load(slots + sbase + k);
        float g = bfhi2f(ent);
        unsigned nb = ent & 0xFFFFu;
        uint4 r0 = P4[(size_t)nb * 8 + j];
        uint4 r1 = P4[((size_t)N + nb) * 8 + j];
        a0[0] += g * bflo2f(r0.x); a0[1] += g * bfhi2f(r0.x);
        a0[2] += g * bflo2f(r0.y); a0[3] += g * bfhi2f(r0.y);
        a0[4] += g * bflo2f(r0.z); a0[5] += g * bfhi2f(r0.z);
        a0[6] += g * bflo2f(r0.w); a0[7] += g * bfhi2f(r0.w);
        a1[0] += g * bflo2f(r1.x); a1[1] += g * bfhi2f(r1.x);
        a1[2] += g * bflo2f(r1.y); a1[3] += g * bfhi2f(r1.y);
        a1[4] += g * bflo2f(r1.z); a1[5] += g * bfhi2f(r1.z);
        a1[6] += g * bflo2f(r1.w); a1[7] += g * bfhi2f(r1.w);
    }

#pragma unroll
    for (int m = 8; m <= 32; m <<= 1) {
#pragma unroll
        for (int i = 0; i < 8; ++i) {
            a0[i] += __shfl_xor(a0[i], m, 64);
            a1[i] += __shfl_xor(a1[i], m, 64);
        }
    }

    if (sub == 0) {
        *(float4*)&xs[wave][0][j * 8]     = make_float4(a0[0], a0[1], a0[2], a0[3]);
        *(float4*)&xs[wave][0][j * 8 + 4] = make_float4(a0[4], a0[5], a0[6], a0[7]);
        *(float4*)&xs[wave][1][j * 8]     = make_float4(a1[0], a1[1], a1[2], a1[3]);
        *(float4*)&xs[wave][1][j * 8 + 4] = make_float4(a1[4], a1[5], a1[6], a1[7]);
    }
    // same-wave LDS dependence: compiler inserts lgkmcnt wait; no barrier.
    float s0 = xs[wave][0][lane];
    float s1 = xs[wave][1][lane];

    size_t b0 = (size_t)n * D + lane;
    size_t b1 = (size_t)N * D + b0;
    float y0 = __builtin_nontemporal_load(node + b0) + s0 +
               __builtin_nontemporal_load(edgef + b0);
    float y1 = __builtin_nontemporal_load(node + b1) + s1 +
               __builtin_nontemporal_load(edgef + b1);
    float r0 = (y0 >= 0.f) ? y0 : 0.01f * y0;
    float r1 = (y1 >= 0.f) ? y1 : 0.01f * y1;
    __builtin_nontemporal_store(r0, out + b0);
    __builtin_nontemporal_store(r1, out + b1);
}

// ===========================================================================
// LAST-RESORT FALLBACK (tiny ws): atomic scatter + separate gemm (fp32 exact)
// ===========================================================================
__device__ inline void atomic_add4(float* p, float4 val, float g) {
    atomicAdd(p + 0, val.x * g);
    atomicAdd(p + 1, val.y * g);
    atomicAdd(p + 2, val.z * g);
    atomicAdd(p + 3, val.w * g);
}

__global__ __launch_bounds__(256) void scatter_kernel(
    const float* __restrict__ prev,
    const int2* __restrict__ edges,
    const float* __restrict__ status,
    float* __restrict__ nbr)
{
    int idx = blockIdx.x * 256 + threadIdx.x;
    int e = idx >> 4;
    int q = idx & 15;
    if (e >= E) return;
    int2 uv = edges[e];
    float g = status[e];
    const float4* p0 = (const float4*)prev;
    const float4* p1 = (const float4*)(prev + (size_t)N * D);
    float4 pu0 = p0[(size_t)uv.x * 16 + q];
    float4 pv0 = p0[(size_t)uv.y * 16 + q];
    float4 pu1 = p1[(size_t)uv.x * 16 + q];
    float4 pv1 = p1[(size_t)uv.y * 16 + q];
    float* n0 = nbr;
    float* n1 = nbr + (size_t)N * D;
    int off_v = uv.y * D + q * 4;
    int off_u = uv.x * D + q * 4;
    atomic_add4(n0 + off_v, pu0, g);
    atomic_add4(n0 + off_u, pv0, g);
    atomic_add4(n1 + off_v, pu1, g);
    atomic_add4(n1 + off_u, pv1, g);
}

__global__ __launch_bounds__(256) void gemm_relu_kernel(
    float* __restrict__ out,
    const float* __restrict__ node,
    const float* __restrict__ edgef,
    const float* __restrict__ W)
{
    __shared__ float Wl[D][D + 1];
    __shared__ float xs[4][D];
    int t = threadIdx.x;
    for (int i = t; i < D * D; i += 256) Wl[i >> 6][i & 63] = W[i];
    int wave = t >> 6, lane = t & 63;
    int row = blockIdx.x * 4 + wave;
    size_t base = (size_t)row * D;
    float x = out[base + lane];
    xs[wave][lane] = x;
    __syncthreads();
    float acc = 0.f;
#pragma unroll
    for (int d = 0; d < D; ++d) acc += xs[wave][d] * Wl[lane][d];
    float y = node[base + lane] + acc + edgef[base + lane];
    out[base + lane] = (y >= 0.f) ? y : 0.01f * y;
}

// ===========================================================================
extern "C" void kernel_launch(void* const* d_in, const int* in_sizes, int n_in,
                              void* d_out, int out_size, void* d_ws, size_t ws_size,
                              hipStream_t stream) {
    const float* prev   = (const float*)d_in[0];
    const int*   edges  = (const int*)d_in[1];
    const float* node   = (const float*)d_in[2];
    const float* edgef  = (const float*)d_in[3];
    const float* status = (const float*)d_in[4];
    const float* W      = (const float*)d_in[5];
    float* out = (float*)d_out;

    const int2* edges2 = (const int2*)edges;

    // ws: slots[N*CAP] u32 | counts[N] i32 | P32[B*N*32] u32
    size_t slots_bytes  = (size_t)N * CAP * sizeof(unsigned);    // 19.2 MB
    size_t counts_bytes = (size_t)N * sizeof(int);               // 0.2 MB
    size_t p_bytes      = (size_t)B * N * 32 * sizeof(unsigned); // 12.8 MB
    size_t need = slots_bytes + counts_bytes + p_bytes;

    if (ws_size >= need) {
        unsigned* slots = (unsigned*)d_ws;
        int* counts = (int*)((char*)d_ws + slots_bytes);
        unsigned* P32 = (unsigned*)((char*)d_ws + slots_bytes + counts_bytes);

        hipMemsetAsync(counts, 0, counts_bytes, stream);
        build_pgemm_fused<<<ECHUNKS * XG + PBLOCKS, 256, 0, stream>>>(
            edges2, status, counts, slots, prev, W, P32);
        gather_final<<<N / 4, 256, 0, stream>>>(
            (const uint4*)P32, counts, slots, node, edgef, out);
    } else {
        hipMemsetAsync(out, 0, (size_t)B * N * D * sizeof(float), stream);
        scatter_kernel<<<(E * 16) / 256, 256, 0, stream>>>(prev, edges2, status, out);
        gemm_relu_kernel<<<(B * N) / 4, 256, 0, stream>>>(out, node, edgef, W);
    }
}

// Round 2
// 312.773 us; speedup vs baseline: 1.0642x; 1.0642x over previous
//
#include <hip/hip_runtime.h>

constexpr int B = 2;
constexpr int N = 50000;
constexpr int D = 64;
constexpr int E = 800000;
constexpr int CAP = 96;        // Poisson(32) max degree over 50k nodes ~58; 96 = margin
constexpr int XG = 8;          // XCD groups
constexpr int NPG = N / XG;    // 6250 nodes per group
constexpr int ECHUNKS = E / 256;          // 3125 build chunks (x8 replicas = 25000 blocks)

// pgemm geometry: wave = 25 rows, block = 4 waves = 100 rows
// -> 1000 pgemm blocks = 125 groups of 8; grid cycle = 25 build groups + 1 pgemm group
constexpr int ROWS_PER_WAVE = 25;
constexpr int PGROUPS = 125;              // (B*N) / (4*ROWS_PER_WAVE*8) = 125
constexpr int TOTAL_GROUPS = ECHUNKS + PGROUPS;   // 3250, cycle length 26

// ---- bf16 helpers (manual RTN) --------------------------------------------
__device__ __forceinline__ unsigned f2bf(float f) {
    unsigned u = __float_as_uint(f);
    return (u + 0x7FFFu + ((u >> 16) & 1u)) >> 16;
}
__device__ __forceinline__ float bfhi2f(unsigned bits) {
    return __uint_as_float(bits & 0xFFFF0000u);
}
__device__ __forceinline__ float bflo2f(unsigned bits) {
    return __uint_as_float(bits << 16);
}

// ===========================================================================
// 1) FUSED build + pgemm, one dispatch. Build path identical to the 303 us
// round-0 kernel (XCD-partitioned slot build, 8 replicas, granularity 8).
// pgemm path rewritten LDS-free: lane = output column, W row held in 64
// VGPRs (loaded once per wave, L1-hot), prev row via wave-uniform s_load,
// 25 rows per wave. Removes ~64 ds_read issues per output row that were
// ~36 us/CU of LDS-pipe issue folded into the old 113 us.
// Grid: cycle of 26 groups = 25 build + 1 pgemm (preserves blockIdx&7 = XCD
// for build; pgemm spread evenly through the dispatch for overlap).
// ===========================================================================
__global__ __launch_bounds__(256) void build_pgemm_fused(
    const int2* __restrict__ edges, const float* __restrict__ status,
    int* __restrict__ counts, unsigned* __restrict__ slots,
    const float* __restrict__ prev, const float* __restrict__ W,
    unsigned* __restrict__ P32)
{
    int grp = blockIdx.x >> 3;
    int sub8 = blockIdx.x & 7;
    int t = threadIdx.x;

    int nm = grp / 26;        // cycle index (0..124)
    int pos = grp % 26;       // position in cycle

    if (pos < 25) {
        // ---- build replica: chunk = nm*25+pos in [0,3125), replica g = sub8
        int chunk = nm * 25 + pos;
        int e = chunk * 256 + t;                  // < E always (3125*256 == E)
        int2 uv = edges[e];
        unsigned gb = f2bf(status[e]) << 16;
        if (uv.x / NPG == sub8) {
            int p = atomicAdd(&counts[uv.x], 1);
            if (p < CAP) slots[(size_t)uv.x * CAP + p] = gb | (unsigned)uv.y;
        }
        if (uv.y / NPG == sub8) {
            int p = atomicAdd(&counts[uv.y], 1);
            if (p < CAP) slots[(size_t)uv.y * CAP + p] = gb | (unsigned)uv.x;
        }
    } else {
        // ---- pgemm: block pb in [0,1000), wave handles 25 rows ------------
        int pb = nm * 8 + sub8;                   // 0..999
        int wave = t >> 6, lane = t & 63;

        // W row `lane` into 64 VGPRs (16 x float4; W is 16 KB, L1-resident)
        const float4* W4 = (const float4*)W;
        float4 w[16];
#pragma unroll
        for (int q = 0; q < 16; ++q) w[q] = W4[lane * 16 + q];

        int row0 = pb * (4 * ROWS_PER_WAVE) + wave * ROWS_PER_WAVE;
        for (int r = 0; r < ROWS_PER_WAVE; ++r) {
            int row = __builtin_amdgcn_readfirstlane(row0 + r);
            const float* pr = prev + (size_t)row * D;   // wave-uniform -> s_load

            float acc = 0.f;
#pragma unroll
            for (int d = 0; d < D; ++d) {
                const float4& wq = w[d >> 2];
                float wd = (d & 3) == 0 ? wq.x : (d & 3) == 1 ? wq.y
                         : (d & 3) == 2 ? wq.z : wq.w;
                acc += pr[d] * wd;
            }

            float partner = __shfl_xor(acc, 1, 64);     // feature lane^1
            if ((lane & 1) == 0) {
                P32[(size_t)row * 32 + (lane >> 1)] = f2bf(acc) | (f2bf(partner) << 16);
            }
        }
    }
}

// ===========================================================================
// 2) Single-pass gather of P rows -> final output (round-0 structure, exact).
// Wave = node (both batches). 8 subs x 8 lanes; per entry 2 x uint4 loads
// (128 B/batch). shfl-reduce across subs; LDS bounce for coalesced epilogue.
// ===========================================================================
__global__ __launch_bounds__(256) void gather_final(
    const uint4* __restrict__ P4,     // (B*N, 8) uint4 rows
    const int* __restrict__ counts,
    const unsigned* __restrict__ slots,
    const float* __restrict__ node,
    const float* __restrict__ edgef,
    float* __restrict__ out)
{
    __shared__ float xs[4][2][D];

    int t = threadIdx.x;
    int wave = t >> 6, lane = t & 63;
    int n = blockIdx.x * 4 + wave;    // grid = N/4 = 12500 exact
    int j = lane & 7;                 // uint4 chunk within row
    int sub = lane >> 3;              // 8-wide entry parallelism

    int cnt = min(counts[n], CAP);
    size_t sbase = (size_t)n * CAP;

    float a0[8], a1[8];
#pragma unroll
    for (int i = 0; i < 8; ++i) { a0[i] = 0.f; a1[i] = 0.f; }

    for (int k = sub; k < cnt; k += 8) {
        unsigned ent = slots[sbase + k];
        float g = bfhi2f(ent);
        unsigned nb = ent & 0xFFFFu;
        uint4 r0 = P4[(size_t)nb * 8 + j];
        uint4 r1 = P4[((size_t)N + nb) * 8 + j];
        a0[0] += g * bflo2f(r0.x); a0[1] += g * bfhi2f(r0.x);
        a0[2] += g * bflo2f(r0.y); a0[3] += g * bfhi2f(r0.y);
        a0[4] += g * bflo2f(r0.z); a0[5] += g * bfhi2f(r0.z);
        a0[6] += g * bflo2f(r0.w); a0[7] += g * bfhi2f(r0.w);
        a1[0] += g * bflo2f(r1.x); a1[1] += g * bfhi2f(r1.x);
        a1[2] += g * bflo2f(r1.y); a1[3] += g * bfhi2f(r1.y);
        a1[4] += g * bflo2f(r1.z); a1[5] += g * bfhi2f(r1.z);
        a1[6] += g * bflo2f(r1.w); a1[7] += g * bfhi2f(r1.w);
    }

#pragma unroll
    for (int m = 8; m <= 32; m <<= 1) {
#pragma unroll
        for (int i = 0; i < 8; ++i) {
            a0[i] += __shfl_xor(a0[i], m, 64);
            a1[i] += __shfl_xor(a1[i], m, 64);
        }
    }

    if (sub == 0) {
        *(float4*)&xs[wave][0][j * 8]     = make_float4(a0[0], a0[1], a0[2], a0[3]);
        *(float4*)&xs[wave][0][j * 8 + 4] = make_float4(a0[4], a0[5], a0[6], a0[7]);
        *(float4*)&xs[wave][1][j * 8]     = make_float4(a1[0], a1[1], a1[2], a1[3]);
        *(float4*)&xs[wave][1][j * 8 + 4] = make_float4(a1[4], a1[5], a1[6], a1[7]);
    }
    // same-wave LDS dependence: compiler inserts lgkmcnt wait; no barrier.
    float s0 = xs[wave][0][lane];
    float s1 = xs[wave][1][lane];

    size_t b0 = (size_t)n * D + lane;
    size_t b1 = (size_t)N * D + b0;
    float y0 = node[b0] + s0 + edgef[b0];
    float y1 = node[b1] + s1 + edgef[b1];
    out[b0] = (y0 >= 0.f) ? y0 : 0.01f * y0;
    out[b1] = (y1 >= 0.f) ? y1 : 0.01f * y1;
}

// ===========================================================================
// LAST-RESORT FALLBACK (tiny ws): atomic scatter + separate gemm (fp32 exact)
// ===========================================================================
__device__ inline void atomic_add4(float* p, float4 val, float g) {
    atomicAdd(p + 0, val.x * g);
    atomicAdd(p + 1, val.y * g);
    atomicAdd(p + 2, val.z * g);
    atomicAdd(p + 3, val.w * g);
}

__global__ __launch_bounds__(256) void scatter_kernel(
    const float* __restrict__ prev,
    const int2* __restrict__ edges,
    const float* __restrict__ status,
    float* __restrict__ nbr)
{
    int idx = blockIdx.x * 256 + threadIdx.x;
    int e = idx >> 4;
    int q = idx & 15;
    if (e >= E) return;
    int2 uv = edges[e];
    float g = status[e];
    const float4* p0 = (const float4*)prev;
    const float4* p1 = (const float4*)(prev + (size_t)N * D);
    float4 pu0 = p0[(size_t)uv.x * 16 + q];
    float4 pv0 = p0[(size_t)uv.y * 16 + q];
    float4 pu1 = p1[(size_t)uv.x * 16 + q];
    float4 pv1 = p1[(size_t)uv.y * 16 + q];
    float* n0 = nbr;
    float* n1 = nbr + (size_t)N * D;
    int off_v = uv.y * D + q * 4;
    int off_u = uv.x * D + q * 4;
    atomic_add4(n0 + off_v, pu0, g);
    atomic_add4(n0 + off_u, pv0, g);
    atomic_add4(n1 + off_v, pu1, g);
    atomic_add4(n1 + off_u, pv1, g);
}

__global__ __launch_bounds__(256) void gemm_relu_kernel(
    float* __restrict__ out,
    const float* __restrict__ node,
    const float* __restrict__ edgef,
    const float* __restrict__ W)
{
    __shared__ float Wl[D][D + 1];
    __shared__ float xs[4][D];
    int t = threadIdx.x;
    for (int i = t; i < D * D; i += 256) Wl[i >> 6][i & 63] = W[i];
    int wave = t >> 6, lane = t & 63;
    int row = blockIdx.x * 4 + wave;
    size_t base = (size_t)row * D;
    float x = out[base + lane];
    xs[wave][lane] = x;
    __syncthreads();
    float acc = 0.f;
#pragma unroll
    for (int d = 0; d < D; ++d) acc += xs[wave][d] * Wl[lane][d];
    float y = node[base + lane] + acc + edgef[base + lane];
    out[base + lane] = (y >= 0.f) ? y : 0.01f * y;
}

// ===========================================================================
extern "C" void kernel_launch(void* const* d_in, const int* in_sizes, int n_in,
                              void* d_out, int out_size, void* d_ws, size_t ws_size,
                              hipStream_t stream) {
    const float* prev   = (const float*)d_in[0];
    const int*   edges  = (const int*)d_in[1];
    const float* node   = (const float*)d_in[2];
    const float* edgef  = (const float*)d_in[3];
    const float* status = (const float*)d_in[4];
    const float* W      = (const float*)d_in[5];
    float* out = (float*)d_out;

    const int2* edges2 = (const int2*)edges;

    // ws: slots[N*CAP] u32 | counts[N] i32 | P32[B*N*32] u32
    size_t slots_bytes  = (size_t)N * CAP * sizeof(unsigned);    // 19.2 MB
    size_t counts_bytes = (size_t)N * sizeof(int);               // 0.2 MB
    size_t p_bytes      = (size_t)B * N * 32 * sizeof(unsigned); // 12.8 MB
    size_t need = slots_bytes + counts_bytes + p_bytes;

    if (ws_size >= need) {
        unsigned* slots = (unsigned*)d_ws;
        int* counts = (int*)((char*)d_ws + slots_bytes);
        unsigned* P32 = (unsigned*)((char*)d_ws + slots_bytes + counts_bytes);

        hipMemsetAsync(counts, 0, counts_bytes, stream);
        build_pgemm_fused<<<TOTAL_GROUPS * 8, 256, 0, stream>>>(
            edges2, status, counts, slots, prev, W, P32);
        gather_final<<<N / 4, 256, 0, stream>>>(
            (const uint4*)P32, counts, slots, node, edgef, out);
    } else {
        hipMemsetAsync(out, 0, (size_t)B * N * D * sizeof(float), stream);
        scatter_kernel<<<(E * 16) / 256, 256, 0, stream>>>(prev, edges2, status, out);
        gemm_relu_kernel<<<(B * N) / 4, 256, 0, stream>>>(out, node, edgef, W);
    }
}

// Round 3
// 272.713 us; speedup vs baseline: 1.2205x; 1.1469x over previous
//
#include <hip/hip_runtime.h>

constexpr int B = 2;
constexpr int N = 50000;
constexpr int D = 64;
constexpr int E = 800000;
constexpr int CAP = 96;        // Poisson(32) max degree over 50k nodes ~58; 96 = margin
constexpr int XG = 8;          // XCD groups
constexpr int NPG = N / XG;    // 6250 nodes per group
constexpr int CSTRIDE_PAD = 16;           // 1 counter per 64B line (anti-serialization)

// build geometry: block = 512 edges (2 per lane, max MLP), 1563 build groups
// pgemm geometry: wave = 25 rows, block = 4 waves -> 1000 blocks = 125 groups
// grid cycle: 12 build groups + 1 pgemm group (first 125 cycles), rest build
constexpr int ROWS_PER_WAVE = 25;
constexpr int BGROUPS = 1563;             // ceil(3125 chunks / 2)
constexpr int PGROUPS = 125;
constexpr int TOTAL_GROUPS = BGROUPS + PGROUPS;   // 1688

// ---- bf16 helpers (manual RTN) --------------------------------------------
__device__ __forceinline__ unsigned f2bf(float f) {
    unsigned u = __float_as_uint(f);
    return (u + 0x7FFFu + ((u >> 16) & 1u)) >> 16;
}
__device__ __forceinline__ float bfhi2f(unsigned bits) {
    return __uint_as_float(bits & 0xFFFF0000u);
}
__device__ __forceinline__ float bflo2f(unsigned bits) {
    return __uint_as_float(bits << 16);
}

// ===========================================================================
// 1) FUSED build + pgemm. Build: XCD-partitioned slot build, 8 replicas,
// granularity 8 (blockIdx&7 = partition, perf heuristic only). This round:
//   - counts padded to 1 per 64B line (cstride, runtime) -> kills same-line
//     atomic serialization at the LLC slice (512 ops/line -> 32 ops/line)
//   - 2 edges per lane, all 4 atomics issued before any dependent store ->
//     2x memory-level parallelism per wave, half the build waves
// pgemm: LDS-free, lane = output column, W row in VGPRs, prev via s_load
// (R2 version, fully hidden under build).
// ===========================================================================
__global__ __launch_bounds__(256) void build_pgemm_fused(
    const int2* __restrict__ edges, const float* __restrict__ status,
    int* __restrict__ counts, unsigned* __restrict__ slots,
    const float* __restrict__ prev, const float* __restrict__ W,
    unsigned* __restrict__ P32, int cstride)
{
    int grp = blockIdx.x >> 3;
    int sub8 = blockIdx.x & 7;
    int t = threadIdx.x;

    int cyc = grp / 13, pos = grp % 13;
    bool is_pgemm = (pos == 12) && (grp < PGROUPS * 13);

    if (!is_pgemm) {
        // ---- build: group b in [0,1563), covers edges [b*512, b*512+512) ---
        int b = (grp < PGROUPS * 13) ? (cyc * 12 + pos) : (1500 + (grp - PGROUPS * 13));
        int e0 = b * 512 + t;             // < E always (1562*512+255 = 799999)
        int e1 = e0 + 256;
        bool has1 = (e1 < E);             // false only in last group (uniform)

        int2 uv0 = edges[e0];
        float st0 = status[e0];
        int2 uv1 = has1 ? edges[e1] : uv0;
        float st1 = has1 ? status[e1] : 0.f;
        unsigned gb0 = f2bf(st0) << 16;
        unsigned gb1 = f2bf(st1) << 16;

        bool du0 = (uv0.x / NPG == sub8);
        bool dv0 = (uv0.y / NPG == sub8);
        bool du1 = has1 && (uv1.x / NPG == sub8);
        bool dv1 = has1 && (uv1.y / NPG == sub8);

        // issue all atomics before consuming any result: 4 independent
        // LLC round trips in flight per lane instead of 1.
        int pu0 = CAP, pv0 = CAP, pu1 = CAP, pv1 = CAP;
        if (du0) pu0 = atomicAdd(&counts[(size_t)uv0.x * cstride], 1);
        if (dv0) pv0 = atomicAdd(&counts[(size_t)uv0.y * cstride], 1);
        if (du1) pu1 = atomicAdd(&counts[(size_t)uv1.x * cstride], 1);
        if (dv1) pv1 = atomicAdd(&counts[(size_t)uv1.y * cstride], 1);
        if (du0 && pu0 < CAP) slots[(size_t)uv0.x * CAP + pu0] = gb0 | (unsigned)uv0.y;
        if (dv0 && pv0 < CAP) slots[(size_t)uv0.y * CAP + pv0] = gb0 | (unsigned)uv0.x;
        if (du1 && pu1 < CAP) slots[(size_t)uv1.x * CAP + pu1] = gb1 | (unsigned)uv1.y;
        if (dv1 && pv1 < CAP) slots[(size_t)uv1.y * CAP + pv1] = gb1 | (unsigned)uv1.x;
    } else {
        // ---- pgemm: block pb in [0,1000), wave handles 25 rows ------------
        int pb = cyc * 8 + sub8;                  // cyc in [0,125)
        int wave = t >> 6, lane = t & 63;

        // W row `lane` into VGPRs (16 x float4; W is 16 KB, L1-resident)
        const float4* W4 = (const float4*)W;
        float4 w[16];
#pragma unroll
        for (int q = 0; q < 16; ++q) w[q] = W4[lane * 16 + q];

        int row0 = pb * (4 * ROWS_PER_WAVE) + wave * ROWS_PER_WAVE;
        for (int r = 0; r < ROWS_PER_WAVE; ++r) {
            int row = __builtin_amdgcn_readfirstlane(row0 + r);
            const float* pr = prev + (size_t)row * D;   // wave-uniform -> s_load

            float acc = 0.f;
#pragma unroll
            for (int d = 0; d < D; ++d) {
                const float4& wq = w[d >> 2];
                float wd = (d & 3) == 0 ? wq.x : (d & 3) == 1 ? wq.y
                         : (d & 3) == 2 ? wq.z : wq.w;
                acc += pr[d] * wd;
            }

            float partner = __shfl_xor(acc, 1, 64);     // feature lane^1
            if ((lane & 1) == 0) {
                P32[(size_t)row * 32 + (lane >> 1)] = f2bf(acc) | (f2bf(partner) << 16);
            }
        }
    }
}

// ===========================================================================
// 2) Single-pass gather of P rows -> final output (round-0 structure, exact).
// Wave = node (both batches). 8 subs x 8 lanes; per entry 2 x uint4 loads
// (128 B/batch). shfl-reduce across subs; LDS bounce for coalesced epilogue.
// ===========================================================================
__global__ __launch_bounds__(256) void gather_final(
    const uint4* __restrict__ P4,     // (B*N, 8) uint4 rows
    const int* __restrict__ counts,
    const unsigned* __restrict__ slots,
    const float* __restrict__ node,
    const float* __restrict__ edgef,
    float* __restrict__ out, int cstride)
{
    __shared__ float xs[4][2][D];

    int t = threadIdx.x;
    int wave = t >> 6, lane = t & 63;
    int n = blockIdx.x * 4 + wave;    // grid = N/4 = 12500 exact
    int j = lane & 7;                 // uint4 chunk within row
    int sub = lane >> 3;              // 8-wide entry parallelism

    int cnt = min(counts[(size_t)n * cstride], CAP);
    size_t sbase = (size_t)n * CAP;

    float a0[8], a1[8];
#pragma unroll
    for (int i = 0; i < 8; ++i) { a0[i] = 0.f; a1[i] = 0.f; }

    for (int k = sub; k < cnt; k += 8) {
        unsigned ent = slots[sbase + k];
        float g = bfhi2f(ent);
        unsigned nb = ent & 0xFFFFu;
        uint4 r0 = P4[(size_t)nb * 8 + j];
        uint4 r1 = P4[((size_t)N + nb) * 8 + j];
        a0[0] += g * bflo2f(r0.x); a0[1] += g * bfhi2f(r0.x);
        a0[2] += g * bflo2f(r0.y); a0[3] += g * bfhi2f(r0.y);
        a0[4] += g * bflo2f(r0.z); a0[5] += g * bfhi2f(r0.z);
        a0[6] += g * bflo2f(r0.w); a0[7] += g * bfhi2f(r0.w);
        a1[0] += g * bflo2f(r1.x); a1[1] += g * bfhi2f(r1.x);
        a1[2] += g * bflo2f(r1.y); a1[3] += g * bfhi2f(r1.y);
        a1[4] += g * bflo2f(r1.z); a1[5] += g * bfhi2f(r1.z);
        a1[6] += g * bflo2f(r1.w); a1[7] += g * bfhi2f(r1.w);
    }

#pragma unroll
    for (int m = 8; m <= 32; m <<= 1) {
#pragma unroll
        for (int i = 0; i < 8; ++i) {
            a0[i] += __shfl_xor(a0[i], m, 64);
            a1[i] += __shfl_xor(a1[i], m, 64);
        }
    }

    if (sub == 0) {
        *(float4*)&xs[wave][0][j * 8]     = make_float4(a0[0], a0[1], a0[2], a0[3]);
        *(float4*)&xs[wave][0][j * 8 + 4] = make_float4(a0[4], a0[5], a0[6], a0[7]);
        *(float4*)&xs[wave][1][j * 8]     = make_float4(a1[0], a1[1], a1[2], a1[3]);
        *(float4*)&xs[wave][1][j * 8 + 4] = make_float4(a1[4], a1[5], a1[6], a1[7]);
    }
    // same-wave LDS dependence: compiler inserts lgkmcnt wait; no barrier.
    float s0 = xs[wave][0][lane];
    float s1 = xs[wave][1][lane];

    size_t b0 = (size_t)n * D + lane;
    size_t b1 = (size_t)N * D + b0;
    float y0 = node[b0] + s0 + edgef[b0];
    float y1 = node[b1] + s1 + edgef[b1];
    out[b0] = (y0 >= 0.f) ? y0 : 0.01f * y0;
    out[b1] = (y1 >= 0.f) ? y1 : 0.01f * y1;
}

// ===========================================================================
// LAST-RESORT FALLBACK (tiny ws): atomic scatter + separate gemm (fp32 exact)
// ===========================================================================
__device__ inline void atomic_add4(float* p, float4 val, float g) {
    atomicAdd(p + 0, val.x * g);
    atomicAdd(p + 1, val.y * g);
    atomicAdd(p + 2, val.z * g);
    atomicAdd(p + 3, val.w * g);
}

__global__ __launch_bounds__(256) void scatter_kernel(
    const float* __restrict__ prev,
    const int2* __restrict__ edges,
    const float* __restrict__ status,
    float* __restrict__ nbr)
{
    int idx = blockIdx.x * 256 + threadIdx.x;
    int e = idx >> 4;
    int q = idx & 15;
    if (e >= E) return;
    int2 uv = edges[e];
    float g = status[e];
    const float4* p0 = (const float4*)prev;
    const float4* p1 = (const float4*)(prev + (size_t)N * D);
    float4 pu0 = p0[(size_t)uv.x * 16 + q];
    float4 pv0 = p0[(size_t)uv.y * 16 + q];
    float4 pu1 = p1[(size_t)uv.x * 16 + q];
    float4 pv1 = p1[(size_t)uv.y * 16 + q];
    float* n0 = nbr;
    float* n1 = nbr + (size_t)N * D;
    int off_v = uv.y * D + q * 4;
    int off_u = uv.x * D + q * 4;
    atomic_add4(n0 + off_v, pu0, g);
    atomic_add4(n0 + off_u, pv0, g);
    atomic_add4(n1 + off_v, pu1, g);
    atomic_add4(n1 + off_u, pv1, g);
}

__global__ __launch_bounds__(256) void gemm_relu_kernel(
    float* __restrict__ out,
    const float* __restrict__ node,
    const float* __restrict__ edgef,
    const float* __restrict__ W)
{
    __shared__ float Wl[D][D + 1];
    __shared__ float xs[4][D];
    int t = threadIdx.x;
    for (int i = t; i < D * D; i += 256) Wl[i >> 6][i & 63] = W[i];
    int wave = t >> 6, lane = t & 63;
    int row = blockIdx.x * 4 + wave;
    size_t base = (size_t)row * D;
    float x = out[base + lane];
    xs[wave][lane] = x;
    __syncthreads();
    float acc = 0.f;
#pragma unroll
    for (int d = 0; d < D; ++d) acc += xs[wave][d] * Wl[lane][d];
    float y = node[base + lane] + acc + edgef[base + lane];
    out[base + lane] = (y >= 0.f) ? y : 0.01f * y;
}

// ===========================================================================
extern "C" void kernel_launch(void* const* d_in, const int* in_sizes, int n_in,
                              void* d_out, int out_size, void* d_ws, size_t ws_size,
                              hipStream_t stream) {
    const float* prev   = (const float*)d_in[0];
    const int*   edges  = (const int*)d_in[1];
    const float* node   = (const float*)d_in[2];
    const float* edgef  = (const float*)d_in[3];
    const float* status = (const float*)d_in[4];
    const float* W      = (const float*)d_in[5];
    float* out = (float*)d_out;

    const int2* edges2 = (const int2*)edges;

    // ws: slots[N*CAP] u32 | counts[N*cstride] i32 | P32[B*N*32] u32
    size_t slots_bytes  = (size_t)N * CAP * sizeof(unsigned);    // 19.2 MB
    size_t p_bytes      = (size_t)B * N * 32 * sizeof(unsigned); // 12.8 MB
    size_t counts_pad   = (size_t)N * CSTRIDE_PAD * sizeof(int); // 3.2 MB
    size_t counts_min   = (size_t)N * sizeof(int);               // 0.2 MB

    int cstride;
    size_t counts_bytes;
    if (ws_size >= slots_bytes + counts_pad + p_bytes) {
        cstride = CSTRIDE_PAD; counts_bytes = counts_pad;
    } else if (ws_size >= slots_bytes + counts_min + p_bytes) {
        cstride = 1; counts_bytes = counts_min;
    } else {
        hipMemsetAsync(out, 0, (size_t)B * N * D * sizeof(float), stream);
        scatter_kernel<<<(E * 16) / 256, 256, 0, stream>>>(prev, edges2, status, out);
        gemm_relu_kernel<<<(B * N) / 4, 256, 0, stream>>>(out, node, edgef, W);
        return;
    }

    unsigned* slots = (unsigned*)d_ws;
    int* counts = (int*)((char*)d_ws + slots_bytes);
    unsigned* P32 = (unsigned*)((char*)d_ws + slots_bytes + counts_bytes);

    hipMemsetAsync(counts, 0, counts_bytes, stream);
    build_pgemm_fused<<<TOTAL_GROUPS * 8, 256, 0, stream>>>(
        edges2, status, counts, slots, prev, W, P32, cstride);
    gather_final<<<N / 4, 256, 0, stream>>>(
        (const uint4*)P32, counts, slots, node, edgef, out, cstride);
}

// Round 5
// 265.411 us; speedup vs baseline: 1.2541x; 1.0275x over previous
//
#include <hip/hip_runtime.h>

constexpr int B = 2;
constexpr int N = 50000;
constexpr int D = 64;
constexpr int E = 800000;
constexpr int CAP = 96;        // Poisson(32) max degree over 50k nodes ~58; 96 = margin
constexpr int XG = 8;          // XCD groups
constexpr int NPG = N / XG;    // 6250 nodes per group
constexpr int CSTRIDE_PAD = 16;           // 1 counter per 64B line

// build geometry: block = 512 edges (2 per lane), 1563 build groups
// pgemm geometry: wave = 25 rows, block = 4 waves -> 1000 blocks = 125 groups
// grid cycle: 12 build groups + 1 pgemm group (first 125 cycles), rest build
constexpr int ROWS_PER_WAVE = 25;
constexpr int BGROUPS = 1563;             // ceil(3125 chunks / 2)
constexpr int PGROUPS = 125;
constexpr int TOTAL_GROUPS = BGROUPS + PGROUPS;   // 1688

// ---- bf16 helpers (manual RTN) --------------------------------------------
__device__ __forceinline__ unsigned f2bf(float f) {
    unsigned u = __float_as_uint(f);
    return (u + 0x7FFFu + ((u >> 16) & 1u)) >> 16;
}
__device__ __forceinline__ float bfhi2f(unsigned bits) {
    return __uint_as_float(bits & 0xFFFF0000u);
}
__device__ __forceinline__ float bflo2f(unsigned bits) {
    return __uint_as_float(bits << 16);
}

__device__ __forceinline__ void acc8(float g, const uint4& r, float* a) {
    a[0] += g * bflo2f(r.x); a[1] += g * bfhi2f(r.x);
    a[2] += g * bflo2f(r.y); a[3] += g * bfhi2f(r.y);
    a[4] += g * bflo2f(r.z); a[5] += g * bfhi2f(r.z);
    a[6] += g * bflo2f(r.w); a[7] += g * bfhi2f(r.w);
}

// ===========================================================================
// 1) FUSED build + pgemm — UNCHANGED from round 3 (110 us; atomic-floor-bound:
// invariant at ~110-113 us across occupancy 42-66%, 1-2 edges/lane, padded or
// unpadded counts -> throughput wall of 1.6M agent atomics + scattered stores).
// ===========================================================================
__global__ __launch_bounds__(256) void build_pgemm_fused(
    const int2* __restrict__ edges, const float* __restrict__ status,
    int* __restrict__ counts, unsigned* __restrict__ slots,
    const float* __restrict__ prev, const float* __restrict__ W,
    unsigned* __restrict__ P32, int cstride)
{
    int grp = blockIdx.x >> 3;
    int sub8 = blockIdx.x & 7;
    int t = threadIdx.x;

    int cyc = grp / 13, pos = grp % 13;
    bool is_pgemm = (pos == 12) && (grp < PGROUPS * 13);

    if (!is_pgemm) {
        int b = (grp < PGROUPS * 13) ? (cyc * 12 + pos) : (1500 + (grp - PGROUPS * 13));
        int e0 = b * 512 + t;
        int e1 = e0 + 256;
        bool has1 = (e1 < E);

        int2 uv0 = edges[e0];
        float st0 = status[e0];
        int2 uv1 = has1 ? edges[e1] : uv0;
        float st1 = has1 ? status[e1] : 0.f;
        unsigned gb0 = f2bf(st0) << 16;
        unsigned gb1 = f2bf(st1) << 16;

        bool du0 = (uv0.x / NPG == sub8);
        bool dv0 = (uv0.y / NPG == sub8);
        bool du1 = has1 && (uv1.x / NPG == sub8);
        bool dv1 = has1 && (uv1.y / NPG == sub8);

        int pu0 = CAP, pv0 = CAP, pu1 = CAP, pv1 = CAP;
        if (du0) pu0 = atomicAdd(&counts[(size_t)uv0.x * cstride], 1);
        if (dv0) pv0 = atomicAdd(&counts[(size_t)uv0.y * cstride], 1);
        if (du1) pu1 = atomicAdd(&counts[(size_t)uv1.x * cstride], 1);
        if (dv1) pv1 = atomicAdd(&counts[(size_t)uv1.y * cstride], 1);
        if (du0 && pu0 < CAP) slots[(size_t)uv0.x * CAP + pu0] = gb0 | (unsigned)uv0.y;
        if (dv0 && pv0 < CAP) slots[(size_t)uv0.y * CAP + pv0] = gb0 | (unsigned)uv0.x;
        if (du1 && pu1 < CAP) slots[(size_t)uv1.x * CAP + pu1] = gb1 | (unsigned)uv1.y;
        if (dv1 && pv1 < CAP) slots[(size_t)uv1.y * CAP + pv1] = gb1 | (unsigned)uv1.x;
    } else {
        int pb = cyc * 8 + sub8;
        int wave = t >> 6, lane = t & 63;

        const float4* W4 = (const float4*)W;
        float4 w[16];
#pragma unroll
        for (int q = 0; q < 16; ++q) w[q] = W4[lane * 16 + q];

        int row0 = pb * (4 * ROWS_PER_WAVE) + wave * ROWS_PER_WAVE;
        for (int r = 0; r < ROWS_PER_WAVE; ++r) {
            int row = __builtin_amdgcn_readfirstlane(row0 + r);
            const float* pr = prev + (size_t)row * D;   // wave-uniform -> s_load

            float acc = 0.f;
#pragma unroll
            for (int d = 0; d < D; ++d) {
                const float4& wq = w[d >> 2];
                float wd = (d & 3) == 0 ? wq.x : (d & 3) == 1 ? wq.y
                         : (d & 3) == 2 ? wq.z : wq.w;
                acc += pr[d] * wd;
            }

            float partner = __shfl_xor(acc, 1, 64);
            if ((lane & 1) == 0) {
                P32[(size_t)row * 32 + (lane >> 1)] = f2bf(acc) | (f2bf(partner) << 16);
            }
        }
    }
}

// ===========================================================================
// 2) Gather, MLP-restructured. Old loop was a 2-deep dependent chain per
// entry (slots load -> P loads) x cnt/8 serial iterations -> latency-bound
// at ~2x its traffic roofline. New: chunks of 32 entries (8 subs x 4): issue
// 4 independent slot loads | wait | 8 independent P loads | wait | 64 FMA.
// Out-of-range k handled by index clamp (always-valid memory) + g=0 mask;
// per-lane summation order identical to previous version (bit-exact).
// node/edgef loads hoisted above the loop to hide their HBM latency.
// ===========================================================================
__global__ __launch_bounds__(256) void gather_final(
    const uint4* __restrict__ P4,     // (B*N, 8) uint4 rows
    const int* __restrict__ counts,
    const unsigned* __restrict__ slots,
    const float* __restrict__ node,
    const float* __restrict__ edgef,
    float* __restrict__ out, int cstride)
{
    __shared__ float xs[4][2][D];

    int t = threadIdx.x;
    int wave = t >> 6, lane = t & 63;
    int n = blockIdx.x * 4 + wave;    // grid = N/4 = 12500 exact
    int j = lane & 7;                 // uint4 chunk within row
    int sub = lane >> 3;              // 8-wide entry parallelism

    size_t b0 = (size_t)n * D + lane;
    size_t b1 = (size_t)N * D + b0;
    // hoisted streams: HBM latency overlaps the gather chains below
    float nd0 = node[b0];
    float ef0 = edgef[b0];
    float nd1 = node[b1];
    float ef1 = edgef[b1];

    int cnt = min(counts[(size_t)n * cstride], CAP);
    size_t sbase = (size_t)n * CAP;

    float a0[8], a1[8];
#pragma unroll
    for (int i = 0; i < 8; ++i) { a0[i] = 0.f; a1[i] = 0.f; }

    int last = cnt - 1;
    int nch = (cnt + 31) >> 5;        // chunks of 32 entries; avg cnt=32 -> 1
    for (int c = 0; c < nch; ++c) {
        int k0 = sub + c * 32;
        // 4 independent slot-entry loads (clamped: positions < cnt are all
        // valid-written; extras masked via g=0)
        unsigned e0 = slots[sbase + min(k0,      last)];
        unsigned e1 = slots[sbase + min(k0 + 8,  last)];
        unsigned e2 = slots[sbase + min(k0 + 16, last)];
        unsigned e3 = slots[sbase + min(k0 + 24, last)];
        float g0 = (k0      < cnt) ? bfhi2f(e0) : 0.f;
        float g1 = (k0 + 8  < cnt) ? bfhi2f(e1) : 0.f;
        float g2 = (k0 + 16 < cnt) ? bfhi2f(e2) : 0.f;
        float g3 = (k0 + 24 < cnt) ? bfhi2f(e3) : 0.f;
        unsigned m0 = e0 & 0xFFFFu, m1 = e1 & 0xFFFFu;
        unsigned m2 = e2 & 0xFFFFu, m3 = e3 & 0xFFFFu;
        // 8 independent P-row loads, all in flight together
        uint4 r00 = P4[(size_t)m0 * 8 + j];
        uint4 r10 = P4[((size_t)N + m0) * 8 + j];
        uint4 r01 = P4[(size_t)m1 * 8 + j];
        uint4 r11 = P4[((size_t)N + m1) * 8 + j];
        uint4 r02 = P4[(size_t)m2 * 8 + j];
        uint4 r12 = P4[((size_t)N + m2) * 8 + j];
        uint4 r03 = P4[(size_t)m3 * 8 + j];
        uint4 r13 = P4[((size_t)N + m3) * 8 + j];
        acc8(g0, r00, a0); acc8(g0, r10, a1);
        acc8(g1, r01, a0); acc8(g1, r11, a1);
        acc8(g2, r02, a0); acc8(g2, r12, a1);
        acc8(g3, r03, a0); acc8(g3, r13, a1);
    }

#pragma unroll
    for (int m = 8; m <= 32; m <<= 1) {
#pragma unroll
        for (int i = 0; i < 8; ++i) {
            a0[i] += __shfl_xor(a0[i], m, 64);
            a1[i] += __shfl_xor(a1[i], m, 64);
        }
    }

    if (sub == 0) {
        *(float4*)&xs[wave][0][j * 8]     = make_float4(a0[0], a0[1], a0[2], a0[3]);
        *(float4*)&xs[wave][0][j * 8 + 4] = make_float4(a0[4], a0[5], a0[6], a0[7]);
        *(float4*)&xs[wave][1][j * 8]     = make_float4(a1[0], a1[1], a1[2], a1[3]);
        *(float4*)&xs[wave][1][j * 8 + 4] = make_float4(a1[4], a1[5], a1[6], a1[7]);
    }
    // same-wave LDS dependence: compiler inserts lgkmcnt wait; no barrier.
    float s0 = xs[wave][0][lane];
    float s1 = xs[wave][1][lane];

    float y0 = nd0 + s0 + ef0;
    float y1 = nd1 + s1 + ef1;
    out[b0] = (y0 >= 0.f) ? y0 : 0.01f * y0;
    out[b1] = (y1 >= 0.f) ? y1 : 0.01f * y1;
}

// ===========================================================================
// LAST-RESORT FALLBACK (tiny ws): atomic scatter + separate gemm (fp32 exact)
// ===========================================================================
__device__ inline void atomic_add4(float* p, float4 val, float g) {
    atomicAdd(p + 0, val.x * g);
    atomicAdd(p + 1, val.y * g);
    atomicAdd(p + 2, val.z * g);
    atomicAdd(p + 3, val.w * g);
}

__global__ __launch_bounds__(256) void scatter_kernel(
    const float* __restrict__ prev,
    const int2* __restrict__ edges,
    const float* __restrict__ status,
    float* __restrict__ nbr)
{
    int idx = blockIdx.x * 256 + threadIdx.x;
    int e = idx >> 4;
    int q = idx & 15;
    if (e >= E) return;
    int2 uv = edges[e];
    float g = status[e];
    const float4* p0 = (const float4*)prev;
    const float4* p1 = (const float4*)(prev + (size_t)N * D);
    float4 pu0 = p0[(size_t)uv.x * 16 + q];
    float4 pv0 = p0[(size_t)uv.y * 16 + q];
    float4 pu1 = p1[(size_t)uv.x * 16 + q];
    float4 pv1 = p1[(size_t)uv.y * 16 + q];
    float* n0 = nbr;
    float* n1 = nbr + (size_t)N * D;
    int off_v = uv.y * D + q * 4;
    int off_u = uv.x * D + q * 4;
    atomic_add4(n0 + off_v, pu0, g);
    atomic_add4(n0 + off_u, pv0, g);
    atomic_add4(n1 + off_v, pu1, g);
    atomic_add4(n1 + off_u, pv1, g);
}

__global__ __launch_bounds__(256) void gemm_relu_kernel(
    float* __restrict__ out,
    const float* __restrict__ node,
    const float* __restrict__ edgef,
    const float* __restrict__ W)
{
    __shared__ float Wl[D][D + 1];
    __shared__ float xs[4][D];
    int t = threadIdx.x;
    for (int i = t; i < D * D; i += 256) Wl[i >> 6][i & 63] = W[i];
    int wave = t >> 6, lane = t & 63;
    int row = blockIdx.x * 4 + wave;
    size_t base = (size_t)row * D;
    float x = out[base + lane];
    xs[wave][lane] = x;
    __syncthreads();
    float acc = 0.f;
#pragma unroll
    for (int d = 0; d < D; ++d) acc += xs[wave][d] * Wl[lane][d];
    float y = node[base + lane] + acc + edgef[base + lane];
    out[base + lane] = (y >= 0.f) ? y : 0.01f * y;
}

// ===========================================================================
extern "C" void kernel_launch(void* const* d_in, const int* in_sizes, int n_in,
                              void* d_out, int out_size, void* d_ws, size_t ws_size,
                              hipStream_t stream) {
    const float* prev   = (const float*)d_in[0];
    const int*   edges  = (const int*)d_in[1];
    const float* node   = (const float*)d_in[2];
    const float* edgef  = (const float*)d_in[3];
    const float* status = (const float*)d_in[4];
    const float* W      = (const float*)d_in[5];
    float* out = (float*)d_out;

    const int2* edges2 = (const int2*)edges;

    // ws: slots[N*CAP] u32 | counts[N*cstride] i32 | P32[B*N*32] u32
    size_t slots_bytes  = (size_t)N * CAP * sizeof(unsigned);    // 19.2 MB
    size_t p_bytes      = (size_t)B * N * 32 * sizeof(unsigned); // 12.8 MB
    size_t counts_pad   = (size_t)N * CSTRIDE_PAD * sizeof(int); // 3.2 MB
    size_t counts_min   = (size_t)N * sizeof(int);               // 0.2 MB

    int cstride;
    size_t counts_bytes;
    if (ws_size >= slots_bytes + counts_pad + p_bytes) {
        cstride = CSTRIDE_PAD; counts_bytes = counts_pad;
    } else if (ws_size >= slots_bytes + counts_min + p_bytes) {
        cstride = 1; counts_bytes = counts_min;
    } else {
        hipMemsetAsync(out, 0, (size_t)B * N * D * sizeof(float), stream);
        scatter_kernel<<<(E * 16) / 256, 256, 0, stream>>>(prev, edges2, status, out);
        gemm_relu_kernel<<<(B * N) / 4, 256, 0, stream>>>(out, node, edgef, W);
        return;
    }

    unsigned* slots = (unsigned*)d_ws;
    int* counts = (int*)((char*)d_ws + slots_bytes);
    unsigned* P32 = (unsigned*)((char*)d_ws + slots_bytes + counts_bytes);

    hipMemsetAsync(counts, 0, counts_bytes, stream);
    build_pgemm_fused<<<TOTAL_GROUPS * 8, 256, 0, stream>>>(
        edges2, status, counts, slots, prev, W, P32, cstride);
    gather_final<<<N / 4, 256, 0, stream>>>(
        (const uint4*)P32, counts, slots, node, edgef, out, cstride);
}